// Round 4
// baseline (112.613 us; speedup 1.0000x reference)
//
#include <hip/hip_runtime.h>

// SpikeLoss: loss = 0.5 * sum((outputs - psp(target))^2)
// psp_t = (1/tau) * sum_{s<=t} d^{t-s} x_s, d = 1-1/tau  (T=32, last axis).
// Lane owns 4 consecutive t (one float4); 8 lanes per row. Fully coalesced.
//
// R3 post-mortem: sched_barrier(0)+U8+same-address-atomics regressed (57 us,
// occupancy 63->41%) — order-pinning defeats the scheduler (Common-mistake #5).
// R4: exact R2 loop body (49.5 us, ~94% of copy ceiling for the main kernel),
// single kernel via last-block-finishes reduction to remove the second
// launch + drain (~3-4 us structural overhead). Deterministic: partials
// summed in fixed order by one block.

#define NBLOCKS 2048
#define NTHREADS 256

__device__ __forceinline__ float process_one(
    float4 x, float4 o, int j,
    float d, float d2, float d3, float d4, float d8, float d16, float inv_tau)
{
    // local inclusive scan over 4 time steps
    float s0 = x.x;
    float s1 = s0 * d + x.y;
    float s2 = s1 * d + x.z;
    float s3 = s2 * d + x.w;

    // weighted Kogge-Stone inclusive scan of segment totals across 8 lanes
    float S = s3;
    float u;
    u = __shfl_up(S, 1, 8); S += (j >= 1) ? d4  * u : 0.0f;
    u = __shfl_up(S, 2, 8); S += (j >= 2) ? d8  * u : 0.0f;
    u = __shfl_up(S, 4, 8); S += (j >= 4) ? d16 * u : 0.0f;

    // carry-in from previous lanes: contribution at local k is d^{k+1} * S_{j-1}
    float cp = __shfl_up(S, 1, 8);
    cp = (j >= 1) ? cp : 0.0f;
    s0 += cp * d;
    s1 += cp * d2;
    s2 += cp * d3;
    s3 += cp * d4;

    float e0 = o.x - s0 * inv_tau;
    float e1 = o.y - s1 * inv_tau;
    float e2 = o.z - s2 * inv_tau;
    float e3 = o.w - s3 * inv_tau;
    return e0 * e0 + e1 * e1 + e2 * e2 + e3 * e3;
}

__global__ __launch_bounds__(NTHREADS) void spike_loss_main(
    const float* __restrict__ outputs,
    const float* __restrict__ target,
    const int* __restrict__ tau_p,
    float* __restrict__ partials,      // d_ws[0 .. NBLOCKS)
    unsigned int* __restrict__ ticket, // d_ws + NBLOCKS (zeroed per call)
    float* __restrict__ out,
    int total4)
{
    const float tau = (float)tau_p[0];
    const float d  = 1.0f - 1.0f / tau;   // 0.75 for tau=4 (exact)
    const float inv_tau = 1.0f / tau;
    const float d2 = d * d;
    const float d3 = d2 * d;
    const float d4 = d2 * d2;
    const float d8 = d4 * d4;
    const float d16 = d8 * d8;

    const int lane = threadIdx.x & 63;
    const int j = lane & 7;               // position within 8-lane row segment

    const float4* __restrict__ t4 = (const float4*)target;
    const float4* __restrict__ o4 = (const float4*)outputs;

    float acc = 0.0f;
    const int stride = gridDim.x * blockDim.x;
    int g = blockIdx.x * blockDim.x + threadIdx.x;

    // main loop: 4 float4-pairs in flight before dependent math (R2 structure)
    for (; g + 3 * stride < total4; g += 4 * stride) {
        float4 x0 = t4[g];
        float4 x1 = t4[g + stride];
        float4 x2 = t4[g + 2 * stride];
        float4 x3 = t4[g + 3 * stride];
        float4 o0 = o4[g];
        float4 o1 = o4[g + stride];
        float4 o2 = o4[g + 2 * stride];
        float4 o3 = o4[g + 3 * stride];

        acc += process_one(x0, o0, j, d, d2, d3, d4, d8, d16, inv_tau);
        acc += process_one(x1, o1, j, d, d2, d3, d4, d8, d16, inv_tau);
        acc += process_one(x2, o2, j, d, d2, d3, d4, d8, d16, inv_tau);
        acc += process_one(x3, o3, j, d, d2, d3, d4, d8, d16, inv_tau);
    }
    // tail (not taken for the bench shape; segments stay convergent since
    // stride and total4 are multiples of 8)
    for (; g < total4; g += stride) {
        acc += process_one(t4[g], o4[g], j, d, d2, d3, d4, d8, d16, inv_tau);
    }

    // wave reduce (64 lanes)
    #pragma unroll
    for (int o = 32; o > 0; o >>= 1) acc += __shfl_down(acc, o, 64);

    __shared__ float wsum[NTHREADS / 64];
    __shared__ bool isLast;
    if (lane == 0) wsum[threadIdx.x >> 6] = acc;
    __syncthreads();
    if (threadIdx.x == 0) {
        float s = 0.0f;
        #pragma unroll
        for (int w = 0; w < NTHREADS / 64; ++w) s += wsum[w];
        partials[blockIdx.x] = s;
        __threadfence();  // device-scope: partial visible across XCDs (G16)
        unsigned int t = atomicAdd(ticket, 1u);
        isLast = (t == (unsigned int)(gridDim.x - 1));
    }
    __syncthreads();

    if (isLast) {
        __threadfence();  // acquire side
        float a = 0.0f;
        for (int i = threadIdx.x; i < NBLOCKS; i += NTHREADS) a += partials[i];
        #pragma unroll
        for (int o = 32; o > 0; o >>= 1) a += __shfl_down(a, o, 64);
        if (lane == 0) wsum[threadIdx.x >> 6] = a;
        __syncthreads();
        if (threadIdx.x == 0) {
            float s = 0.0f;
            #pragma unroll
            for (int w = 0; w < NTHREADS / 64; ++w) s += wsum[w];
            out[0] = 0.5f * s;
        }
    }
}

extern "C" void kernel_launch(void* const* d_in, const int* in_sizes, int n_in,
                              void* d_out, int out_size, void* d_ws, size_t ws_size,
                              hipStream_t stream) {
    const float* outputs = (const float*)d_in[0];
    const float* target  = (const float*)d_in[1];
    // d_in[2] = n_steps (T=32 baked into the 8-lane-per-row layout)
    const int*   tau_p   = (const int*)d_in[3];

    float*        partials = (float*)d_ws;                 // NBLOCKS floats
    unsigned int* ticket   = (unsigned int*)((char*)d_ws + NBLOCKS * sizeof(float));

    const int total4 = in_sizes[0] / 4;

    hipMemsetAsync(ticket, 0, sizeof(unsigned int), stream);  // reset ticket each call
    spike_loss_main<<<NBLOCKS, NTHREADS, 0, stream>>>(
        outputs, target, tau_p, partials, ticket, (float*)d_out, total4);
}

// Round 5
// 57.815 us; speedup vs baseline: 1.9478x; 1.9478x over previous
//
#include <hip/hip_runtime.h>

// SpikeLoss: loss = 0.5 * sum((outputs - psp(target))^2)
// psp_t = (1/tau) * sum_{s<=t} d^{t-s} x_s, d = 1-1/tau  (T=32, last axis).
// Lane owns 4 consecutive t (one float4); 8 lanes per row. Fully coalesced.
//
// R4 post-mortem: last-block pattern's device-scope __threadfence() per block
// forces L2 writeback/invalidate on non-coherent per-XCD L2s -> read BW halved
// (112 us). Cross-block data via non-atomic stores+fence is poison (G16);
// atomics alone are cheap.
// R5: exact R2 loop body (proven 49.5 us, VGPR 28, occ 63%) + fence-free
// single-kernel ending: per-block atomicAdd(out) after a memset node.

#define NBLOCKS 2048
#define NTHREADS 256

__device__ __forceinline__ float process_one(
    float4 x, float4 o, int j,
    float d, float d2, float d3, float d4, float d8, float d16, float inv_tau)
{
    // local inclusive scan over 4 time steps
    float s0 = x.x;
    float s1 = s0 * d + x.y;
    float s2 = s1 * d + x.z;
    float s3 = s2 * d + x.w;

    // weighted Kogge-Stone inclusive scan of segment totals across 8 lanes
    float S = s3;
    float u;
    u = __shfl_up(S, 1, 8); S += (j >= 1) ? d4  * u : 0.0f;
    u = __shfl_up(S, 2, 8); S += (j >= 2) ? d8  * u : 0.0f;
    u = __shfl_up(S, 4, 8); S += (j >= 4) ? d16 * u : 0.0f;

    // carry-in from previous lanes: contribution at local k is d^{k+1} * S_{j-1}
    float cp = __shfl_up(S, 1, 8);
    cp = (j >= 1) ? cp : 0.0f;
    s0 += cp * d;
    s1 += cp * d2;
    s2 += cp * d3;
    s3 += cp * d4;

    float e0 = o.x - s0 * inv_tau;
    float e1 = o.y - s1 * inv_tau;
    float e2 = o.z - s2 * inv_tau;
    float e3 = o.w - s3 * inv_tau;
    return e0 * e0 + e1 * e1 + e2 * e2 + e3 * e3;
}

__global__ __launch_bounds__(NTHREADS) void spike_loss_fused(
    const float* __restrict__ outputs,
    const float* __restrict__ target,
    const int* __restrict__ tau_p,
    float* __restrict__ out,
    int total4)
{
    const float tau = (float)tau_p[0];
    const float d  = 1.0f - 1.0f / tau;   // 0.75 for tau=4 (exact)
    const float inv_tau = 1.0f / tau;
    const float d2 = d * d;
    const float d3 = d2 * d;
    const float d4 = d2 * d2;
    const float d8 = d4 * d4;
    const float d16 = d8 * d8;

    const int lane = threadIdx.x & 63;
    const int j = lane & 7;               // position within 8-lane row segment

    const float4* __restrict__ t4 = (const float4*)target;
    const float4* __restrict__ o4 = (const float4*)outputs;

    float acc = 0.0f;
    const int stride = gridDim.x * blockDim.x;
    int g = blockIdx.x * blockDim.x + threadIdx.x;

    // main loop: 4 float4-pairs in flight before dependent math (R2 structure)
    for (; g + 3 * stride < total4; g += 4 * stride) {
        float4 x0 = t4[g];
        float4 x1 = t4[g + stride];
        float4 x2 = t4[g + 2 * stride];
        float4 x3 = t4[g + 3 * stride];
        float4 o0 = o4[g];
        float4 o1 = o4[g + stride];
        float4 o2 = o4[g + 2 * stride];
        float4 o3 = o4[g + 3 * stride];

        acc += process_one(x0, o0, j, d, d2, d3, d4, d8, d16, inv_tau);
        acc += process_one(x1, o1, j, d, d2, d3, d4, d8, d16, inv_tau);
        acc += process_one(x2, o2, j, d, d2, d3, d4, d8, d16, inv_tau);
        acc += process_one(x3, o3, j, d, d2, d3, d4, d8, d16, inv_tau);
    }
    // tail (not taken for the bench shape; segments stay convergent since
    // stride and total4 are multiples of 8)
    for (; g < total4; g += stride) {
        acc += process_one(t4[g], o4[g], j, d, d2, d3, d4, d8, d16, inv_tau);
    }

    // wave reduce (64 lanes)
    #pragma unroll
    for (int o = 32; o > 0; o >>= 1) acc += __shfl_down(acc, o, 64);

    __shared__ float wsum[NTHREADS / 64];
    if (lane == 0) wsum[threadIdx.x >> 6] = acc;
    __syncthreads();
    if (threadIdx.x == 0) {
        float s = 0.0f;
        #pragma unroll
        for (int w = 0; w < NTHREADS / 64; ++w) s += wsum[w];
        atomicAdd(out, 0.5f * s);   // coherent by itself; no fence needed
    }
}

extern "C" void kernel_launch(void* const* d_in, const int* in_sizes, int n_in,
                              void* d_out, int out_size, void* d_ws, size_t ws_size,
                              hipStream_t stream) {
    const float* outputs = (const float*)d_in[0];
    const float* target  = (const float*)d_in[1];
    // d_in[2] = n_steps (T=32 baked into the 8-lane-per-row layout)
    const int*   tau_p   = (const int*)d_in[3];

    const int total4 = in_sizes[0] / 4;

    hipMemsetAsync(d_out, 0, sizeof(float), stream);   // graph-capturable zeroing node
    spike_loss_fused<<<NBLOCKS, NTHREADS, 0, stream>>>(
        outputs, target, tau_p, (float*)d_out, total4);
}